// Round 17
// baseline (179.766 us; speedup 1.0000x reference)
//
#include <hip/hip_runtime.h>
#include <hip/hip_bf16.h>

#define SS 2048
#define DD 128
#define HH 16
#define BB 2
#define HD 2048   // H*D
#define BS 4096   // B*S

typedef __attribute__((ext_vector_type(4))) float f32x4;
typedef __attribute__((ext_vector_type(8))) short s16x8;

__device__ __forceinline__ short f2bf(float f) {
    union { __hip_bfloat16 h; short s; } u;
    u.h = __float2bfloat16(f);
    return u.s;
}
__device__ __forceinline__ float bf2f(short s) {
    union { unsigned u; float f; } w;
    w.u = ((unsigned)(unsigned short)s) << 16;
    return w.f;
}
__device__ __forceinline__ float us2f(unsigned short s) {
    union { unsigned u; float f; } w;
    w.u = ((unsigned)s) << 16;
    return w.f;
}
__device__ __forceinline__ unsigned cvtpk(float lo, float hi) {
    unsigned r;
    asm("v_cvt_pk_bf16_f32 %0, %1, %2" : "=v"(r) : "v"(lo), "v"(hi));
    return r;
}

// ---- prep_w: W-transposes + Wf hi/lo split. blocks [0,96): wt; [96,128): wf.
__global__ __launch_bounds__(256) void prep_w(
    const float* __restrict__ Wq, const float* __restrict__ Wk, const float* __restrict__ Wv,
    const float* __restrict__ Wf,
    short* __restrict__ WTq, short* __restrict__ WTk, short* __restrict__ WTv,
    short* __restrict__ Whi, short* __restrict__ Wlo)
{
    __shared__ float t[64][129];
    int bb = blockIdx.x;
    int tid = threadIdx.x;

    if (bb < 96) {
        int z = bb >> 5;
        const float* W = (z==0) ? Wq : (z==1) ? Wk : Wv;
        short* WT      = (z==0) ? WTq : (z==1) ? WTk : WTv;
        int c0 = (bb & 31) * 64;
        #pragma unroll 4
        for (int i = 0; i < 32; ++i) {
            int idx = i*256 + tid;
            int k = idx >> 6, c = idx & 63;
            t[c][k] = W[(size_t)k * HD + c0 + c];
        }
        __syncthreads();
        #pragma unroll 4
        for (int i = 0; i < 32; ++i) {
            int idx = i*256 + tid;
            int c = idx >> 7, k = idx & 127;
            WT[(size_t)(c0 + c) * DD + k] = f2bf(t[c][k]);
        }
    } else {
        int b2 = bb - 96;
        int k0 = (b2 & 15) * 128;
        int j0 = (b2 >> 4) * 64;
        #pragma unroll 4
        for (int i = 0; i < 32; ++i) {
            int idx = i*256 + tid;
            int kk = idx >> 6, jj = idx & 63;
            t[jj][kk] = Wf[(size_t)(k0 + kk) * DD + j0 + jj];
        }
        __syncthreads();
        #pragma unroll 4
        for (int i = 0; i < 32; ++i) {
            int idx = i*256 + tid;
            int jj = idx >> 7, kk = idx & 127;
            float v = t[jj][kk];
            short hb = f2bf(v);
            Whi[(size_t)(j0 + jj) * HD + k0 + kk] = hb;
            Wlo[(size_t)(j0 + jj) * HD + k0 + kk] = f2bf(v - bf2f(hb));
        }
    }
}

// ---- projmask: proj units [0,1536) + mask_perm units [1536,5632) in one grid.
__global__ __launch_bounds__(256, 2) void projmask_kernel(
    const float* __restrict__ Xq, const float* __restrict__ Xk, const float* __restrict__ Xv,
    const float* __restrict__ m,
    const short* __restrict__ WTq, const short* __restrict__ WTk, const short* __restrict__ WTv,
    const float* __restrict__ bq, const float* __restrict__ bk, const float* __restrict__ bv,
    short* __restrict__ Yq, short* __restrict__ Yk, short* __restrict__ Yv,
    unsigned short* __restrict__ mp)
{
    __shared__ alignas(16) char Wl[128 * 256];   // 32 KB
    const int u = blockIdx.x;
    const int tid = threadIdx.x;

    if (u >= 1536) {
        // ---- mask_perm (verified r8 layout), value scaled by log2e ----
        const float LOG2E = 1.44269504088896340736f;
        int o8 = (u - 1536) * 256 + tid;
        int g    = o8 & 3;
        int lane = (o8 >> 2) & 63;
        int kt   = (o8 >> 8) & 31;
        int band = (o8 >> 13) & 63;
        int b    = o8 >> 19;
        int lr = lane & 15, lg = lane >> 4;
        int rt = g >> 1;
        int row  = band*32 + rt*16 + lr;
        int colb = kt*64 + (g & 1)*32 + lg*4;
        const float* src = m + (size_t)b * SS * SS + (size_t)row * SS;
        f32x4 v0 = *reinterpret_cast<const f32x4*>(src + colb);
        f32x4 v1 = *reinterpret_cast<const f32x4*>(src + colb + 16);
        s16x8 o;
        #pragma unroll
        for (int j = 0; j < 4; ++j) { o[j] = f2bf(v0[j]*LOG2E); o[4+j] = f2bf(v1[j]*LOG2E); }
        *reinterpret_cast<s16x8*>(mp + (size_t)o8 * 8) = o;
        return;
    }

    // ---- proj unit ----
    int z = u >> 9;
    int bx = u & 511;
    const float* X  = (z==0) ? Xq  : (z==1) ? Xk  : Xv;
    const short* WT = (z==0) ? WTq : (z==1) ? WTk : WTv;
    const float* bias = (z==0) ? bq : (z==1) ? bk : bv;
    short* Y = (z==0) ? Yq : (z==1) ? Yk : Yv;
    const float oscale = (z==0) ? 0.022097086912079608f : 1.0f;  // 1/sqrt(2048)

    int wave = tid >> 6, lane = tid & 63;
    int lr = lane & 15, lg = lane >> 4;
    int rb = bx >> 4, cb = bx & 15;
    int row0 = rb * 128 + wave * 32;
    int col0 = cb * 128;

    #pragma unroll
    for (int p = 0; p < 8; ++p) {
        int crow = p*16 + (tid >> 4), cc = tid & 15;
        *reinterpret_cast<int4*>(Wl + crow*256 + ((cc ^ (crow & 15)) << 4)) =
            *reinterpret_cast<const int4*>(WT + (size_t)(col0 + crow) * DD + cc*8);
    }
    __syncthreads();

    s16x8 afr[2][4];
    #pragma unroll
    for (int rt = 0; rt < 2; ++rt) {
        const float* xrow = X + (size_t)(row0 + rt*16 + lr) * DD + lg * 8;
        #pragma unroll
        for (int c = 0; c < 4; ++c) {
            f32x4 a0 = *reinterpret_cast<const f32x4*>(xrow + c*32);
            f32x4 a1 = *reinterpret_cast<const f32x4*>(xrow + c*32 + 4);
            #pragma unroll
            for (int j = 0; j < 4; ++j) { afr[rt][c][j] = f2bf(a0[j]); afr[rt][c][4+j] = f2bf(a1[j]); }
        }
    }

    f32x4 acc[2][8];
    #pragma unroll
    for (int rt = 0; rt < 2; ++rt)
        #pragma unroll
        for (int tn = 0; tn < 8; ++tn) acc[rt][tn] = (f32x4){0.f, 0.f, 0.f, 0.f};

    #pragma unroll
    for (int tn = 0; tn < 8; ++tn) {
        s16x8 kf[4];
        #pragma unroll
        for (int c = 0; c < 4; ++c)
            kf[c] = *reinterpret_cast<const s16x8*>(
                Wl + (tn*16 + lr)*256 + (((c*4 + lg) ^ lr) << 4));
        #pragma unroll
        for (int rt = 0; rt < 2; ++rt)
            #pragma unroll
            for (int c = 0; c < 4; ++c)
                acc[rt][tn] = __builtin_amdgcn_mfma_f32_16x16x32_bf16(afr[rt][c], kf[c], acc[rt][tn], 0, 0, 0);
    }

    #pragma unroll
    for (int tn = 0; tn < 8; ++tn) {
        float bcol = bias[col0 + tn*16 + lr];
        #pragma unroll
        for (int rt = 0; rt < 2; ++rt) {
            #pragma unroll
            for (int r = 0; r < 4; ++r) {
                int row = row0 + rt*16 + lg*4 + r;
                Y[(size_t)row * HD + col0 + tn*16 + lr] = f2bf((acc[rt][tn][r] + bcol) * oscale);
            }
        }
    }
}

// ---- transpose Yv -> Vt with the sigma column permutation (verified round 8).
__global__ __launch_bounds__(256) void vtrans(
    const short* __restrict__ Yv, short* __restrict__ Vt) {
    __shared__ short t16[16 * 2048];    // 64 KB
    int row0 = blockIdx.x * 16;
    int tid = threadIdx.x;
    #pragma unroll
    for (int i = 0; i < 16; ++i) {
        int chunk = i*256 + tid;
        int rr = chunk >> 8, c8 = chunk & 255;
        *reinterpret_cast<s16x8*>(&t16[rr*2048 + c8*8]) =
            *reinterpret_cast<const s16x8*>(Yv + (size_t)(row0 + rr) * HD + c8*8);
    }
    __syncthreads();
    int bb = row0 >> 11, row2 = row0 & 2047, hh = row2 >> 7, r0 = row2 & 127;
    int s0 = r0 * 16;
    int d = tid & 127, si = tid >> 7;
    short* outbase = Vt + ((size_t)((bb*HH + hh)*DD + d)) * SS;
    #pragma unroll
    for (int i = 0; i < 8; ++i) {
        int run = s0 + si*128 + i*16;
        int r16 = (run - s0) >> 4;
        short v[16];
        #pragma unroll
        for (int j = 0; j < 16; ++j) v[j] = t16[r16*2048 + j*128 + d];
        int blk = run & ~63;
        int t = (run >> 4) & 3;
        short* dstb = outbase + blk + (t >> 1)*32;
        if ((t & 1) == 0) {
            #pragma unroll
            for (int g = 0; g < 4; ++g) {
                uint2 w;
                w.x = (unsigned)(unsigned short)v[g*4]   | ((unsigned)(unsigned short)v[g*4+1] << 16);
                w.y = (unsigned)(unsigned short)v[g*4+2] | ((unsigned)(unsigned short)v[g*4+3] << 16);
                *reinterpret_cast<uint2*>(dstb + g*8) = w;
            }
        } else {
            #pragma unroll
            for (int g = 0; g < 4; ++g) {
                unsigned p0 = (unsigned)(unsigned short)v[g*4]   | ((unsigned)(unsigned short)v[g*4+1] << 16);
                unsigned p1 = (unsigned)(unsigned short)v[g*4+2] | ((unsigned)(unsigned short)v[g*4+3] << 16);
                int off0 = (g < 2) ? g*8 + 6  : g*8 - 12;
                int off1 = (g < 2) ? g*8 + 22 : g*8 + 4;
                *reinterpret_cast<unsigned*>(dstb + off0) = p0;
                *reinterpret_cast<unsigned*>(dstb + off1) = p1;
            }
        }
    }
}

// ---- fused attention (verified-best structure; bf16 Aout epilogue — bit-identical):
//      256-thread block = 4 waves, one head x 128 q-rows, 2 blocks/CU.
//      Double-buffered K/V LDS, ONE barrier/iter. Reg-staged prefetch.
//      Swapped QK^T -> in-register P. Permuted bf16 mask (x log2e), raw v_exp_f32.
__global__ __launch_bounds__(256, 2) void attn_kernel(
    const short* __restrict__ Yq, const short* __restrict__ Yk, const short* __restrict__ Vt,
    const unsigned short* __restrict__ Mp, short* __restrict__ Ah)
{
    __shared__ alignas(16) char Kl[2][64 * 256];   // 32 KB
    __shared__ alignas(16) char Vl[2][128 * 128];  // 32 KB

    const int tid = threadIdx.x;
    const int wave = tid >> 6, lane = tid & 63;
    const int lr = lane & 15, lg = lane >> 4;
    const int h = blockIdx.x, qb = blockIdx.y, b = blockIdx.z;
    const int q0w = qb * 128 + wave * 32;
    const int band = qb * 4 + wave;

    const short* Qb = Yq + (size_t)(b*HH + h) * (SS*DD);
    const short* Kb = Yk + (size_t)(b*HH + h) * (SS*DD);
    const short* Vb = Vt + (size_t)(b*HH + h) * (SS*DD);
    const unsigned short* mrow = Mp + ((size_t)(b*64 + band) * 2048 + lane) * 32;

    // --- staging geometry: per thread 4 K chunks + 4 V chunks of 16B ---
    int kdst[4], vdst[4];
    const short* ksrc[4];
    const short* vsrc[4];
    #pragma unroll
    for (int p = 0; p < 4; ++p) {
        int krow = p*16 + (tid >> 4), kc16 = tid & 15;
        kdst[p] = krow*256 + ((kc16 ^ (krow & 15)) << 4);
        ksrc[p] = Kb + (size_t)krow * DD + kc16*8;
        int vd = p*32 + (tid >> 3), vc8 = tid & 7;
        vdst[p] = vd*128 + ((vc8 ^ (vd & 7)) << 4);
        vsrc[p] = Vb + (size_t)vd * SS + vc8*8;
    }

    // --- Q fragments (B-operand; pre-scaled by 1/sqrt(S)) ---
    s16x8 qf[2][4];
    #pragma unroll
    for (int rt = 0; rt < 2; ++rt) {
        const short* qrow = Qb + (size_t)(q0w + rt*16 + lr) * DD + lg * 8;
        #pragma unroll
        for (int c = 0; c < 4; ++c) qf[rt][c] = *reinterpret_cast<const s16x8*>(qrow + c*32);
    }

    f32x4 o[2][8];
    #pragma unroll
    for (int rt = 0; rt < 2; ++rt)
        #pragma unroll
        for (int dt = 0; dt < 8; ++dt) o[rt][dt] = (f32x4){0.f, 0.f, 0.f, 0.f};
    float ls[2] = {0.f, 0.f};

    // --- prologue: stage tile 0 into buffer 0 ---
    #pragma unroll
    for (int p = 0; p < 4; ++p) {
        *reinterpret_cast<int4*>(Kl[0] + kdst[p]) = *reinterpret_cast<const int4*>(ksrc[p]);
        *reinterpret_cast<int4*>(Vl[0] + vdst[p]) = *reinterpret_cast<const int4*>(vsrc[p]);
    }
    __syncthreads();

    for (int kt = 0; kt < 32; ++kt) {
        const int cur = kt & 1;
        char* Klc = Kl[cur];     char* Vlc = Vl[cur];
        char* Kln = Kl[cur ^ 1]; char* Vln = Vl[cur ^ 1];
        const int kp0 = kt * 64;
        const int kpn = (kt < 31) ? kp0 + 64 : kp0;

        // prefetch next tile into regs
        int4 kreg[4], vreg[4];
        #pragma unroll
        for (int p = 0; p < 4; ++p) {
            kreg[p] = *reinterpret_cast<const int4*>(ksrc[p] + (size_t)kpn * DD);
            vreg[p] = *reinterpret_cast<const int4*>(vsrc[p] + kpn);
        }

        // permuted mask: 4 contiguous b128 loads
        const unsigned short* mptr = mrow + (size_t)kt * 2048;
        s16x8 mk[4];
        mk[0] = *reinterpret_cast<const s16x8*>(mptr);
        mk[1] = *reinterpret_cast<const s16x8*>(mptr + 8);
        mk[2] = *reinterpret_cast<const s16x8*>(mptr + 16);
        mk[3] = *reinterpret_cast<const s16x8*>(mptr + 24);

        // SWAPPED QK^T: lane (lr,lg) reg r = score[q=rt*16+lr][k=t*16+lg*4+r]
        f32x4 st[2][4];
        #pragma unroll
        for (int rt = 0; rt < 2; ++rt)
            #pragma unroll
            for (int t = 0; t < 4; ++t) st[rt][t] = (f32x4){0.f, 0.f, 0.f, 0.f};
        __builtin_amdgcn_s_setprio(1);
        #pragma unroll
        for (int t = 0; t < 4; ++t) {
            s16x8 kf[4];
            #pragma unroll
            for (int c = 0; c < 4; ++c)
                kf[c] = *reinterpret_cast<const s16x8*>(
                    Klc + (t*16 + lr)*256 + (((c*4 + lg) ^ lr) << 4));
            #pragma unroll
            for (int rt = 0; rt < 2; ++rt)
                #pragma unroll
                for (int c = 0; c < 4; ++c)
                    st[rt][t] = __builtin_amdgcn_mfma_f32_16x16x32_bf16(kf[c], qf[rt][c], st[rt][t], 0, 0, 0);
        }
        __builtin_amdgcn_s_setprio(0);

        // mask-mul + raw v_exp_f32 (mask pre-scaled by log2e; |arg| <= ~2.2)
        #pragma unroll
        for (int rt = 0; rt < 2; ++rt) {
            float ps = 0.f;
            #pragma unroll
            for (int t = 0; t < 4; ++t) {
                #pragma unroll
                for (int r = 0; r < 4; ++r) {
                    float mvv = us2f((unsigned short)mk[rt*2 + (t>>1)][(t&1)*4 + r]);
                    st[rt][t][r] = __builtin_amdgcn_exp2f(st[rt][t][r] * mvv);
                    ps += st[rt][t][r];
                }
            }
            ls[rt] += ps;
        }

        // in-register P -> A-frags (verified construction)
        s16x8 pfr[2][2];
        #pragma unroll
        for (int rt = 0; rt < 2; ++rt) {
            #pragma unroll
            for (int c2 = 0; c2 < 2; ++c2) {
                union { unsigned u[4]; s16x8 s; } pk;
                pk.u[0] = cvtpk(st[rt][c2*2][0],   st[rt][c2*2][1]);
                pk.u[1] = cvtpk(st[rt][c2*2][2],   st[rt][c2*2][3]);
                unsigned X = cvtpk(st[rt][c2*2+1][0], st[rt][c2*2+1][1]);
                unsigned Y = cvtpk(st[rt][c2*2+1][2], st[rt][c2*2+1][3]);
                asm("v_permlane32_swap_b32 %0, %1" : "+v"(X), "+v"(Y));
                pk.u[2] = Y;
                pk.u[3] = X;
                pfr[rt][c2] = pk.s;
            }
        }

        // PV: V frags (sigma-permuted) read once, shared across row-tiles
        __builtin_amdgcn_s_setprio(1);
        #pragma unroll
        for (int dt = 0; dt < 8; ++dt) {
            const char* vbase = Vlc + (dt*16 + lr)*128;
            s16x8 vf0 = *reinterpret_cast<const s16x8*>(vbase + (((0*4 + lg) ^ (lr & 7)) << 4));
            s16x8 vf1 = *reinterpret_cast<const s16x8*>(vbase + (((1*4 + lg) ^ (lr & 7)) << 4));
            #pragma unroll
            for (int rt = 0; rt < 2; ++rt) {
                o[rt][dt] = __builtin_amdgcn_mfma_f32_16x16x32_bf16(pfr[rt][0], vf0, o[rt][dt], 0, 0, 0);
                o[rt][dt] = __builtin_amdgcn_mfma_f32_16x16x32_bf16(pfr[rt][1], vf1, o[rt][dt], 0, 0, 0);
            }
        }
        __builtin_amdgcn_s_setprio(0);

        // write next tile; ONE barrier per iteration
        #pragma unroll
        for (int p = 0; p < 4; ++p) {
            *reinterpret_cast<int4*>(Kln + kdst[p]) = kreg[p];
            *reinterpret_cast<int4*>(Vln + vdst[p]) = vreg[p];
        }
        __syncthreads();
    }

    // epilogue: reduce row-sums, normalize, store bf16 (same rounding point as before)
    #pragma unroll
    for (int rt = 0; rt < 2; ++rt) {
        float s = ls[rt];
        s += __shfl_xor(s, 16, 64);
        s += __shfl_xor(s, 32, 64);
        short* orow = Ah + ((size_t)(b*HH + h) * SS + q0w + rt*16) * DD;
        #pragma unroll
        for (int r = 0; r < 4; ++r) {
            float inv = 1.0f / __shfl(s, lg*4 + r, 16);
            #pragma unroll
            for (int dt = 0; dt < 8; ++dt)
                orow[(size_t)(lg*4 + r) * DD + dt*16 + lr] = f2bf(o[rt][dt][r] * inv);
        }
    }
}

// ---- final GEMM: out[4096][128] = A(bf16)[4096][2048] @ Wf + bf, W hi/lo.
//      4 waves split K (512 each); parallel LDS reduce + store (2 tn per wave).
__global__ __launch_bounds__(256) void final_gemm(
    const short* __restrict__ A, const short* __restrict__ Whi, const short* __restrict__ Wlo,
    const float* __restrict__ bfv, float* __restrict__ out)
{
    __shared__ float red[4][2048];   // 32 KB
    int wave = threadIdx.x >> 6, lane = threadIdx.x & 63;
    int lr = lane & 15, lg = lane >> 4;
    int row0 = blockIdx.x * 16;
    int k0 = wave * 512;

    f32x4 acc[8];
    #pragma unroll
    for (int tn = 0; tn < 8; ++tn) acc[tn] = (f32x4){0.f, 0.f, 0.f, 0.f};

    const short* arow = A + (size_t)(row0 + lr) * HD + k0 + lg * 8;
    for (int kc = 0; kc < 16; ++kc) {
        s16x8 ah = *reinterpret_cast<const s16x8*>(arow + kc*32);
        #pragma unroll
        for (int tn = 0; tn < 8; ++tn) {
            const short* whrow = Whi + (size_t)(tn*16 + lr) * HD + k0 + kc*32 + lg*8;
            const short* wlrow = Wlo + (size_t)(tn*16 + lr) * HD + k0 + kc*32 + lg*8;
            s16x8 bh = *reinterpret_cast<const s16x8*>(whrow);
            s16x8 bl = *reinterpret_cast<const s16x8*>(wlrow);
            acc[tn] = __builtin_amdgcn_mfma_f32_16x16x32_bf16(ah, bh, acc[tn], 0, 0, 0);
            acc[tn] = __builtin_amdgcn_mfma_f32_16x16x32_bf16(ah, bl, acc[tn], 0, 0, 0);
        }
    }

    float* rp = red[wave];
    #pragma unroll
    for (int tn = 0; tn < 8; ++tn)
        *reinterpret_cast<f32x4*>(&rp[(tn*64 + lane)*4]) = acc[tn];
    __syncthreads();

    #pragma unroll
    for (int t2 = 0; t2 < 2; ++t2) {
        int tn = wave*2 + t2;
        f32x4 s = *reinterpret_cast<const f32x4*>(&red[0][(tn*64 + lane)*4]);
        #pragma unroll
        for (int w2 = 1; w2 < 4; ++w2)
            s += *reinterpret_cast<const f32x4*>(&red[w2][(tn*64 + lane)*4]);
        float bc = bfv[tn*16 + lr];
        #pragma unroll
        for (int r = 0; r < 4; ++r)
            out[(size_t)(row0 + lg*4 + r) * DD + tn*16 + lr] = s[r] + bc;
    }
}

extern "C" void kernel_launch(void* const* d_in, const int* in_sizes, int n_in,
                              void* d_out, int out_size, void* d_ws, size_t ws_size,
                              hipStream_t stream) {
    const float* v    = (const float*)d_in[0];
    const float* k    = (const float*)d_in[1];
    const float* q    = (const float*)d_in[2];
    const float* mask = (const float*)d_in[3];
    const float* Wq   = (const float*)d_in[4];
    const float* bq   = (const float*)d_in[5];
    const float* Wk   = (const float*)d_in[6];
    const float* bk   = (const float*)d_in[7];
    const float* Wv   = (const float*)d_in[8];
    const float* bv   = (const float*)d_in[9];
    const float* Wf   = (const float*)d_in[10];
    const float* bf   = (const float*)d_in[11];
    float* out = (float*)d_out;

    char* ws = (char*)d_ws;
    size_t off = 0;
    short* Yq   = (short*)(ws + off); off += (size_t)BS * HD * 2;   // 16 MB
    short* Yk   = (short*)(ws + off); off += (size_t)BS * HD * 2;   // 16 MB
    short* Vt   = (short*)(ws + off); off += (size_t)BS * HD * 2;   // 16 MB
    short* Ah   = (short*)(ws + off); off += (size_t)BS * HD * 2;   // 16 MB (bf16 A)
    short* Yv   = Ah;                                               // aliases Ah (sequential use)
    unsigned short* Mp = (unsigned short*)(ws + off); off += (size_t)BB * SS * SS * 2; // 16.8 MB
    short* WTq  = (short*)(ws + off); off += (size_t)HD * DD * 2;
    short* WTk  = (short*)(ws + off); off += (size_t)HD * DD * 2;
    short* WTv  = (short*)(ws + off); off += (size_t)HD * DD * 2;
    short* Wfhi = (short*)(ws + off); off += (size_t)DD * HD * 2;
    short* Wflo = (short*)(ws + off); off += (size_t)DD * HD * 2;

    prep_w<<<dim3(128), 256, 0, stream>>>(Wq, Wk, Wv, Wf, WTq, WTk, WTv, Wfhi, Wflo);
    projmask_kernel<<<dim3(5632), 256, 0, stream>>>(q, k, v, mask, WTq, WTk, WTv,
                                                    bq, bk, bv, Yq, Yk, Yv, Mp);
    vtrans<<<dim3(256), 256, 0, stream>>>(Yv, Vt);
    attn_kernel<<<dim3(16, 16, 2), 256, 0, stream>>>(Yq, Yk, Vt, Mp, Ah);
    final_gemm<<<dim3(256), 256, 0, stream>>>(Ah, Wfhi, Wflo, bf, out);
}

// Round 18
// 177.033 us; speedup vs baseline: 1.0154x; 1.0154x over previous
//
#include <hip/hip_runtime.h>
#include <hip/hip_bf16.h>

#define SS 2048
#define DD 128
#define HH 16
#define BB 2
#define HD 2048   // H*D
#define BS 4096   // B*S

typedef __attribute__((ext_vector_type(4))) float f32x4;
typedef __attribute__((ext_vector_type(8))) short s16x8;

__device__ __forceinline__ short f2bf(float f) {
    union { __hip_bfloat16 h; short s; } u;
    u.h = __float2bfloat16(f);
    return u.s;
}
__device__ __forceinline__ float bf2f(short s) {
    union { unsigned u; float f; } w;
    w.u = ((unsigned)(unsigned short)s) << 16;
    return w.f;
}
__device__ __forceinline__ float us2f(unsigned short s) {
    union { unsigned u; float f; } w;
    w.u = ((unsigned)s) << 16;
    return w.f;
}
__device__ __forceinline__ unsigned cvtpk(float lo, float hi) {
    unsigned r;
    asm("v_cvt_pk_bf16_f32 %0, %1, %2" : "=v"(r) : "v"(lo), "v"(hi));
    return r;
}

// ---- prep_w: W-transposes + Wf hi/lo split. blocks [0,96): wt; [96,128): wf.
__global__ __launch_bounds__(256) void prep_w(
    const float* __restrict__ Wq, const float* __restrict__ Wk, const float* __restrict__ Wv,
    const float* __restrict__ Wf,
    short* __restrict__ WTq, short* __restrict__ WTk, short* __restrict__ WTv,
    short* __restrict__ Whi, short* __restrict__ Wlo)
{
    __shared__ float t[64][129];
    int bb = blockIdx.x;
    int tid = threadIdx.x;

    if (bb < 96) {
        int z = bb >> 5;
        const float* W = (z==0) ? Wq : (z==1) ? Wk : Wv;
        short* WT      = (z==0) ? WTq : (z==1) ? WTk : WTv;
        int c0 = (bb & 31) * 64;
        #pragma unroll 4
        for (int i = 0; i < 32; ++i) {
            int idx = i*256 + tid;
            int k = idx >> 6, c = idx & 63;
            t[c][k] = W[(size_t)k * HD + c0 + c];
        }
        __syncthreads();
        #pragma unroll 4
        for (int i = 0; i < 32; ++i) {
            int idx = i*256 + tid;
            int c = idx >> 7, k = idx & 127;
            WT[(size_t)(c0 + c) * DD + k] = f2bf(t[c][k]);
        }
    } else {
        int b2 = bb - 96;
        int k0 = (b2 & 15) * 128;
        int j0 = (b2 >> 4) * 64;
        #pragma unroll 4
        for (int i = 0; i < 32; ++i) {
            int idx = i*256 + tid;
            int kk = idx >> 6, jj = idx & 63;
            t[jj][kk] = Wf[(size_t)(k0 + kk) * DD + j0 + jj];
        }
        __syncthreads();
        #pragma unroll 4
        for (int i = 0; i < 32; ++i) {
            int idx = i*256 + tid;
            int jj = idx >> 7, kk = idx & 127;
            float v = t[jj][kk];
            short hb = f2bf(v);
            Whi[(size_t)(j0 + jj) * HD + k0 + kk] = hb;
            Wlo[(size_t)(j0 + jj) * HD + k0 + kk] = f2bf(v - bf2f(hb));
        }
    }
}

// ---- projmask: proj units [0,1536) + mask_perm units [1536,5632) in one grid.
__global__ __launch_bounds__(256, 2) void projmask_kernel(
    const float* __restrict__ Xq, const float* __restrict__ Xk, const float* __restrict__ Xv,
    const float* __restrict__ m,
    const short* __restrict__ WTq, const short* __restrict__ WTk, const short* __restrict__ WTv,
    const float* __restrict__ bq, const float* __restrict__ bk, const float* __restrict__ bv,
    short* __restrict__ Yq, short* __restrict__ Yk, short* __restrict__ Yv,
    unsigned short* __restrict__ mp)
{
    __shared__ alignas(16) char Wl[128 * 256];   // 32 KB
    const int u = blockIdx.x;
    const int tid = threadIdx.x;

    if (u >= 1536) {
        // ---- mask_perm (verified r8 layout), value scaled by log2e ----
        const float LOG2E = 1.44269504088896340736f;
        int o8 = (u - 1536) * 256 + tid;
        int g    = o8 & 3;
        int lane = (o8 >> 2) & 63;
        int kt   = (o8 >> 8) & 31;
        int band = (o8 >> 13) & 63;
        int b    = o8 >> 19;
        int lr = lane & 15, lg = lane >> 4;
        int rt = g >> 1;
        int row  = band*32 + rt*16 + lr;
        int colb = kt*64 + (g & 1)*32 + lg*4;
        const float* src = m + (size_t)b * SS * SS + (size_t)row * SS;
        f32x4 v0 = *reinterpret_cast<const f32x4*>(src + colb);
        f32x4 v1 = *reinterpret_cast<const f32x4*>(src + colb + 16);
        s16x8 o;
        #pragma unroll
        for (int j = 0; j < 4; ++j) { o[j] = f2bf(v0[j]*LOG2E); o[4+j] = f2bf(v1[j]*LOG2E); }
        *reinterpret_cast<s16x8*>(mp + (size_t)o8 * 8) = o;
        return;
    }

    // ---- proj unit ----
    int z = u >> 9;
    int bx = u & 511;
    const float* X  = (z==0) ? Xq  : (z==1) ? Xk  : Xv;
    const short* WT = (z==0) ? WTq : (z==1) ? WTk : WTv;
    const float* bias = (z==0) ? bq : (z==1) ? bk : bv;
    short* Y = (z==0) ? Yq : (z==1) ? Yk : Yv;
    const float oscale = (z==0) ? 0.022097086912079608f : 1.0f;  // 1/sqrt(2048)

    int wave = tid >> 6, lane = tid & 63;
    int lr = lane & 15, lg = lane >> 4;
    int rb = bx >> 4, cb = bx & 15;
    int row0 = rb * 128 + wave * 32;
    int col0 = cb * 128;

    #pragma unroll
    for (int p = 0; p < 8; ++p) {
        int crow = p*16 + (tid >> 4), cc = tid & 15;
        *reinterpret_cast<int4*>(Wl + crow*256 + ((cc ^ (crow & 15)) << 4)) =
            *reinterpret_cast<const int4*>(WT + (size_t)(col0 + crow) * DD + cc*8);
    }
    __syncthreads();

    s16x8 afr[2][4];
    #pragma unroll
    for (int rt = 0; rt < 2; ++rt) {
        const float* xrow = X + (size_t)(row0 + rt*16 + lr) * DD + lg * 8;
        #pragma unroll
        for (int c = 0; c < 4; ++c) {
            f32x4 a0 = *reinterpret_cast<const f32x4*>(xrow + c*32);
            f32x4 a1 = *reinterpret_cast<const f32x4*>(xrow + c*32 + 4);
            #pragma unroll
            for (int j = 0; j < 4; ++j) { afr[rt][c][j] = f2bf(a0[j]); afr[rt][c][4+j] = f2bf(a1[j]); }
        }
    }

    f32x4 acc[2][8];
    #pragma unroll
    for (int rt = 0; rt < 2; ++rt)
        #pragma unroll
        for (int tn = 0; tn < 8; ++tn) acc[rt][tn] = (f32x4){0.f, 0.f, 0.f, 0.f};

    #pragma unroll
    for (int tn = 0; tn < 8; ++tn) {
        s16x8 kf[4];
        #pragma unroll
        for (int c = 0; c < 4; ++c)
            kf[c] = *reinterpret_cast<const s16x8*>(
                Wl + (tn*16 + lr)*256 + (((c*4 + lg) ^ lr) << 4));
        #pragma unroll
        for (int rt = 0; rt < 2; ++rt)
            #pragma unroll
            for (int c = 0; c < 4; ++c)
                acc[rt][tn] = __builtin_amdgcn_mfma_f32_16x16x32_bf16(afr[rt][c], kf[c], acc[rt][tn], 0, 0, 0);
    }

    #pragma unroll
    for (int tn = 0; tn < 8; ++tn) {
        float bcol = bias[col0 + tn*16 + lr];
        #pragma unroll
        for (int rt = 0; rt < 2; ++rt) {
            #pragma unroll
            for (int r = 0; r < 4; ++r) {
                int row = row0 + rt*16 + lg*4 + r;
                Y[(size_t)row * HD + col0 + tn*16 + lr] = f2bf((acc[rt][tn][r] + bcol) * oscale);
            }
        }
    }
}

// ---- transpose Yv -> Vt with sigma (verified r8 math; 8-row/512-block tiling
//      verified inside the round-14 mega-kernel P2).
__global__ __launch_bounds__(256) void vtrans(
    const short* __restrict__ Yv, short* __restrict__ Vt) {
    __shared__ short t16[8 * 2048];    // 32 KB
    int row0 = blockIdx.x * 8;
    int tid = threadIdx.x;
    #pragma unroll
    for (int i = 0; i < 8; ++i) {
        int chunk = i*256 + tid;         // 0..2047
        int rr = chunk >> 8, c8 = chunk & 255;
        *reinterpret_cast<s16x8*>(&t16[rr*2048 + c8*8]) =
            *reinterpret_cast<const s16x8*>(Yv + (size_t)(row0 + rr) * HD + c8*8);
    }
    __syncthreads();
    int bb = row0 >> 11, row2 = row0 & 2047, hh = row2 >> 7, r0 = row2 & 127;
    int s0 = r0 * 16;
    int d = tid & 127, si = tid >> 7;    // si 0..1
    short* outbase = Vt + ((size_t)((bb*HH + hh)*DD + d)) * SS;
    #pragma unroll
    for (int i = 0; i < 4; ++i) {
        int run = s0 + si*64 + i*16;
        int r16 = (run - s0) >> 4;
        short v[16];
        #pragma unroll
        for (int j = 0; j < 16; ++j) v[j] = t16[r16*2048 + j*128 + d];
        int blk = run & ~63;
        int t = (run >> 4) & 3;
        short* dstb = outbase + blk + (t >> 1)*32;
        if ((t & 1) == 0) {
            #pragma unroll
            for (int g = 0; g < 4; ++g) {
                uint2 w;
                w.x = (unsigned)(unsigned short)v[g*4]   | ((unsigned)(unsigned short)v[g*4+1] << 16);
                w.y = (unsigned)(unsigned short)v[g*4+2] | ((unsigned)(unsigned short)v[g*4+3] << 16);
                *reinterpret_cast<uint2*>(dstb + g*8) = w;
            }
        } else {
            #pragma unroll
            for (int g = 0; g < 4; ++g) {
                unsigned p0 = (unsigned)(unsigned short)v[g*4]   | ((unsigned)(unsigned short)v[g*4+1] << 16);
                unsigned p1 = (unsigned)(unsigned short)v[g*4+2] | ((unsigned)(unsigned short)v[g*4+3] << 16);
                int off0 = (g < 2) ? g*8 + 6  : g*8 - 12;
                int off1 = (g < 2) ? g*8 + 22 : g*8 + 4;
                *reinterpret_cast<unsigned*>(dstb + off0) = p0;
                *reinterpret_cast<unsigned*>(dstb + off1) = p1;
            }
        }
    }
}

// ---- fused attention (verified-best; bf16 Aout epilogue, bit-identical numerics):
//      256-thread block = 4 waves, one head x 128 q-rows, 2 blocks/CU.
//      Double-buffered K/V LDS, ONE barrier/iter. Reg-staged prefetch.
//      Swapped QK^T -> in-register P. Permuted bf16 mask (x log2e), raw v_exp_f32.
__global__ __launch_bounds__(256, 2) void attn_kernel(
    const short* __restrict__ Yq, const short* __restrict__ Yk, const short* __restrict__ Vt,
    const unsigned short* __restrict__ Mp, short* __restrict__ Ah)
{
    __shared__ alignas(16) char Kl[2][64 * 256];   // 32 KB
    __shared__ alignas(16) char Vl[2][128 * 128];  // 32 KB

    const int tid = threadIdx.x;
    const int wave = tid >> 6, lane = tid & 63;
    const int lr = lane & 15, lg = lane >> 4;
    const int h = blockIdx.x, qb = blockIdx.y, b = blockIdx.z;
    const int q0w = qb * 128 + wave * 32;
    const int band = qb * 4 + wave;

    const short* Qb = Yq + (size_t)(b*HH + h) * (SS*DD);
    const short* Kb = Yk + (size_t)(b*HH + h) * (SS*DD);
    const short* Vb = Vt + (size_t)(b*HH + h) * (SS*DD);
    const unsigned short* mrow = Mp + ((size_t)(b*64 + band) * 2048 + lane) * 32;

    // --- staging geometry: per thread 4 K chunks + 4 V chunks of 16B ---
    int kdst[4], vdst[4];
    const short* ksrc[4];
    const short* vsrc[4];
    #pragma unroll
    for (int p = 0; p < 4; ++p) {
        int krow = p*16 + (tid >> 4), kc16 = tid & 15;
        kdst[p] = krow*256 + ((kc16 ^ (krow & 15)) << 4);
        ksrc[p] = Kb + (size_t)krow * DD + kc16*8;
        int vd = p*32 + (tid >> 3), vc8 = tid & 7;
        vdst[p] = vd*128 + ((vc8 ^ (vd & 7)) << 4);
        vsrc[p] = Vb + (size_t)vd * SS + vc8*8;
    }

    // --- Q fragments (B-operand; pre-scaled by 1/sqrt(S)) ---
    s16x8 qf[2][4];
    #pragma unroll
    for (int rt = 0; rt < 2; ++rt) {
        const short* qrow = Qb + (size_t)(q0w + rt*16 + lr) * DD + lg * 8;
        #pragma unroll
        for (int c = 0; c < 4; ++c) qf[rt][c] = *reinterpret_cast<const s16x8*>(qrow + c*32);
    }

    f32x4 o[2][8];
    #pragma unroll
    for (int rt = 0; rt < 2; ++rt)
        #pragma unroll
        for (int dt = 0; dt < 8; ++dt) o[rt][dt] = (f32x4){0.f, 0.f, 0.f, 0.f};
    float ls[2] = {0.f, 0.f};

    // --- prologue: stage tile 0 into buffer 0 ---
    #pragma unroll
    for (int p = 0; p < 4; ++p) {
        *reinterpret_cast<int4*>(Kl[0] + kdst[p]) = *reinterpret_cast<const int4*>(ksrc[p]);
        *reinterpret_cast<int4*>(Vl[0] + vdst[p]) = *reinterpret_cast<const int4*>(vsrc[p]);
    }
    __syncthreads();

    for (int kt = 0; kt < 32; ++kt) {
        const int cur = kt & 1;
        char* Klc = Kl[cur];     char* Vlc = Vl[cur];
        char* Kln = Kl[cur ^ 1]; char* Vln = Vl[cur ^ 1];
        const int kp0 = kt * 64;
        const int kpn = (kt < 31) ? kp0 + 64 : kp0;

        // prefetch next tile into regs
        int4 kreg[4], vreg[4];
        #pragma unroll
        for (int p = 0; p < 4; ++p) {
            kreg[p] = *reinterpret_cast<const int4*>(ksrc[p] + (size_t)kpn * DD);
            vreg[p] = *reinterpret_cast<const int4*>(vsrc[p] + kpn);
        }

        // permuted mask: 4 contiguous b128 loads
        const unsigned short* mptr = mrow + (size_t)kt * 2048;
        s16x8 mk[4];
        mk[0] = *reinterpret_cast<const s16x8*>(mptr);
        mk[1] = *reinterpret_cast<const s16x8*>(mptr + 8);
        mk[2] = *reinterpret_cast<const s16x8*>(mptr + 16);
        mk[3] = *reinterpret_cast<const s16x8*>(mptr + 24);

        // SWAPPED QK^T: lane (lr,lg) reg r = score[q=rt*16+lr][k=t*16+lg*4+r]
        f32x4 st[2][4];
        #pragma unroll
        for (int rt = 0; rt < 2; ++rt)
            #pragma unroll
            for (int t = 0; t < 4; ++t) st[rt][t] = (f32x4){0.f, 0.f, 0.f, 0.f};
        __builtin_amdgcn_s_setprio(1);
        #pragma unroll
        for (int t = 0; t < 4; ++t) {
            s16x8 kf[4];
            #pragma unroll
            for (int c = 0; c < 4; ++c)
                kf[c] = *reinterpret_cast<const s16x8*>(
                    Klc + (t*16 + lr)*256 + (((c*4 + lg) ^ lr) << 4));
            #pragma unroll
            for (int rt = 0; rt < 2; ++rt)
                #pragma unroll
                for (int c = 0; c < 4; ++c)
                    st[rt][t] = __builtin_amdgcn_mfma_f32_16x16x32_bf16(kf[c], qf[rt][c], st[rt][t], 0, 0, 0);
        }
        __builtin_amdgcn_s_setprio(0);

        // mask-mul + raw v_exp_f32 (mask pre-scaled by log2e; |arg| <= ~2.2)
        #pragma unroll
        for (int rt = 0; rt < 2; ++rt) {
            float ps = 0.f;
            #pragma unroll
            for (int t = 0; t < 4; ++t) {
                #pragma unroll
                for (int r = 0; r < 4; ++r) {
                    float mvv = us2f((unsigned short)mk[rt*2 + (t>>1)][(t&1)*4 + r]);
                    st[rt][t][r] = __builtin_amdgcn_exp2f(st[rt][t][r] * mvv);
                    ps += st[rt][t][r];
                }
            }
            ls[rt] += ps;
        }

        // in-register P -> A-frags (verified construction)
        s16x8 pfr[2][2];
        #pragma unroll
        for (int rt = 0; rt < 2; ++rt) {
            #pragma unroll
            for (int c2 = 0; c2 < 2; ++c2) {
                union { unsigned u[4]; s16x8 s; } pk;
                pk.u[0] = cvtpk(st[rt][c2*2][0],   st[rt][c2*2][1]);
                pk.u[1] = cvtpk(st[rt][c2*2][2],   st[rt][c2*2][3]);
                unsigned X = cvtpk(st[rt][c2*2+1][0], st[rt][c2*2+1][1]);
                unsigned Y = cvtpk(st[rt][c2*2+1][2], st[rt][c2*2+1][3]);
                asm("v_permlane32_swap_b32 %0, %1" : "+v"(X), "+v"(Y));
                pk.u[2] = Y;
                pk.u[3] = X;
                pfr[rt][c2] = pk.s;
            }
        }

        // PV: V frags (sigma-permuted) read once, shared across row-tiles
        __builtin_amdgcn_s_setprio(1);
        #pragma unroll
        for (int dt = 0; dt < 8; ++dt) {
            const char* vbase = Vlc + (dt*16 + lr)*128;
            s16x8 vf0 = *reinterpret_cast<const s16x8*>(vbase + (((0*4 + lg) ^ (lr & 7)) << 4));
            s16x8 vf1 = *reinterpret_cast<const s16x8*>(vbase + (((1*4 + lg) ^ (lr & 7)) << 4));
            #pragma unroll
            for (int rt = 0; rt < 2; ++rt) {
                o[rt][dt] = __builtin_amdgcn_mfma_f32_16x16x32_bf16(pfr[rt][0], vf0, o[rt][dt], 0, 0, 0);
                o[rt][dt] = __builtin_amdgcn_mfma_f32_16x16x32_bf16(pfr[rt][1], vf1, o[rt][dt], 0, 0, 0);
            }
        }
        __builtin_amdgcn_s_setprio(0);

        // write next tile; ONE barrier per iteration
        #pragma unroll
        for (int p = 0; p < 4; ++p) {
            *reinterpret_cast<int4*>(Kln + kdst[p]) = kreg[p];
            *reinterpret_cast<int4*>(Vln + vdst[p]) = vreg[p];
        }
        __syncthreads();
    }

    // epilogue: reduce row-sums, normalize, store bf16 (same rounding point as before)
    #pragma unroll
    for (int rt = 0; rt < 2; ++rt) {
        float s = ls[rt];
        s += __shfl_xor(s, 16, 64);
        s += __shfl_xor(s, 32, 64);
        short* orow = Ah + ((size_t)(b*HH + h) * SS + q0w + rt*16) * DD;
        #pragma unroll
        for (int r = 0; r < 4; ++r) {
            float inv = 1.0f / __shfl(s, lg*4 + r, 16);
            #pragma unroll
            for (int dt = 0; dt < 8; ++dt)
                orow[(size_t)(lg*4 + r) * DD + dt*16 + lr] = f2bf(o[rt][dt][r] * inv);
        }
    }
}

// ---- final GEMM: out[4096][128] = A(bf16)[4096][2048] @ Wf + bf, W hi/lo.
//      4 waves split K (512 each); parallel LDS reduce + store (2 tn per wave).
__global__ __launch_bounds__(256) void final_gemm(
    const short* __restrict__ A, const short* __restrict__ Whi, const short* __restrict__ Wlo,
    const float* __restrict__ bfv, float* __restrict__ out)
{
    __shared__ float red[4][2048];   // 32 KB
    int wave = threadIdx.x >> 6, lane = threadIdx.x & 63;
    int lr = lane & 15, lg = lane >> 4;
    int row0 = blockIdx.x * 16;
    int k0 = wave * 512;

    f32x4 acc[8];
    #pragma unroll
    for (int tn = 0; tn < 8; ++tn) acc[tn] = (f32x4){0.f, 0.f, 0.f, 0.f};

    const short* arow = A + (size_t)(row0 + lr) * HD + k0 + lg * 8;
    for (int kc = 0; kc < 16; ++kc) {
        s16x8 ah = *reinterpret_cast<const s16x8*>(arow + kc*32);
        #pragma unroll
        for (int tn = 0; tn < 8; ++tn) {
            const short* whrow = Whi + (size_t)(tn*16 + lr) * HD + k0 + kc*32 + lg*8;
            const short* wlrow = Wlo + (size_t)(tn*16 + lr) * HD + k0 + kc*32 + lg*8;
            s16x8 bh = *reinterpret_cast<const s16x8*>(whrow);
            s16x8 bl = *reinterpret_cast<const s16x8*>(wlrow);
            acc[tn] = __builtin_amdgcn_mfma_f32_16x16x32_bf16(ah, bh, acc[tn], 0, 0, 0);
            acc[tn] = __builtin_amdgcn_mfma_f32_16x16x32_bf16(ah, bl, acc[tn], 0, 0, 0);
        }
    }

    float* rp = red[wave];
    #pragma unroll
    for (int tn = 0; tn < 8; ++tn)
        *reinterpret_cast<f32x4*>(&rp[(tn*64 + lane)*4]) = acc[tn];
    __syncthreads();

    #pragma unroll
    for (int t2 = 0; t2 < 2; ++t2) {
        int tn = wave*2 + t2;
        f32x4 s = *reinterpret_cast<const f32x4*>(&red[0][(tn*64 + lane)*4]);
        #pragma unroll
        for (int w2 = 1; w2 < 4; ++w2)
            s += *reinterpret_cast<const f32x4*>(&red[w2][(tn*64 + lane)*4]);
        float bc = bfv[tn*16 + lr];
        #pragma unroll
        for (int r = 0; r < 4; ++r)
            out[(size_t)(row0 + lg*4 + r) * DD + tn*16 + lr] = s[r] + bc;
    }
}

extern "C" void kernel_launch(void* const* d_in, const int* in_sizes, int n_in,
                              void* d_out, int out_size, void* d_ws, size_t ws_size,
                              hipStream_t stream) {
    const float* v    = (const float*)d_in[0];
    const float* k    = (const float*)d_in[1];
    const float* q    = (const float*)d_in[2];
    const float* mask = (const float*)d_in[3];
    const float* Wq   = (const float*)d_in[4];
    const float* bq   = (const float*)d_in[5];
    const float* Wk   = (const float*)d_in[6];
    const float* bk   = (const float*)d_in[7];
    const float* Wv   = (const float*)d_in[8];
    const float* bv   = (const float*)d_in[9];
    const float* Wf   = (const float*)d_in[10];
    const float* bf   = (const float*)d_in[11];
    float* out = (float*)d_out;

    char* ws = (char*)d_ws;
    size_t off = 0;
    short* Yq   = (short*)(ws + off); off += (size_t)BS * HD * 2;   // 16 MB
    short* Yk   = (short*)(ws + off); off += (size_t)BS * HD * 2;   // 16 MB
    short* Vt   = (short*)(ws + off); off += (size_t)BS * HD * 2;   // 16 MB
    short* Ah   = (short*)(ws + off); off += (size_t)BS * HD * 2;   // 16 MB (bf16 A)
    short* Yv   = Ah;                                               // aliases Ah (sequential use)
    unsigned short* Mp = (unsigned short*)(ws + off); off += (size_t)BB * SS * SS * 2; // 16.8 MB
    short* WTq  = (short*)(ws + off); off += (size_t)HD * DD * 2;
    short* WTk  = (short*)(ws + off); off += (size_t)HD * DD * 2;
    short* WTv  = (short*)(ws + off); off += (size_t)HD * DD * 2;
    short* Wfhi = (short*)(ws + off); off += (size_t)DD * HD * 2;
    short* Wflo = (short*)(ws + off); off += (size_t)DD * HD * 2;

    prep_w<<<dim3(128), 256, 0, stream>>>(Wq, Wk, Wv, Wf, WTq, WTk, WTv, Wfhi, Wflo);
    projmask_kernel<<<dim3(5632), 256, 0, stream>>>(q, k, v, mask, WTq, WTk, WTv,
                                                    bq, bk, bv, Yq, Yk, Yv, Mp);
    vtrans<<<dim3(512), 256, 0, stream>>>(Yv, Vt);
    attn_kernel<<<dim3(16, 16, 2), 256, 0, stream>>>(Yq, Yk, Vt, Mp, Ah);
    final_gemm<<<dim3(256), 256, 0, stream>>>(Ah, Wfhi, Wflo, bf, out);
}

// Round 19
// 165.172 us; speedup vs baseline: 1.0884x; 1.0718x over previous
//
#include <hip/hip_runtime.h>
#include <hip/hip_bf16.h>

#define SS 2048
#define DD 128
#define HH 16
#define BB 2
#define HD 2048   // H*D
#define BS 4096   // B*S

typedef __attribute__((ext_vector_type(4))) float f32x4;
typedef __attribute__((ext_vector_type(8))) short s16x8;

__device__ __forceinline__ short f2bf(float f) {
    union { __hip_bfloat16 h; short s; } u;
    u.h = __float2bfloat16(f);
    return u.s;
}
__device__ __forceinline__ float bf2f(short s) {
    union { unsigned u; float f; } w;
    w.u = ((unsigned)(unsigned short)s) << 16;
    return w.f;
}
__device__ __forceinline__ float us2f(unsigned short s) {
    union { unsigned u; float f; } w;
    w.u = ((unsigned)s) << 16;
    return w.f;
}
__device__ __forceinline__ unsigned cvtpk(float lo, float hi) {
    unsigned r;
    asm("v_cvt_pk_bf16_f32 %0, %1, %2" : "=v"(r) : "v"(lo), "v"(hi));
    return r;
}

// ---- prep_w: W-transposes + Wf hi/lo split. blocks [0,96): wt; [96,128): wf.
__global__ __launch_bounds__(256) void prep_w(
    const float* __restrict__ Wq, const float* __restrict__ Wk, const float* __restrict__ Wv,
    const float* __restrict__ Wf,
    short* __restrict__ WTq, short* __restrict__ WTk, short* __restrict__ WTv,
    short* __restrict__ Whi, short* __restrict__ Wlo)
{
    __shared__ float t[64][129];
    int bb = blockIdx.x;
    int tid = threadIdx.x;

    if (bb < 96) {
        int z = bb >> 5;
        const float* W = (z==0) ? Wq : (z==1) ? Wk : Wv;
        short* WT      = (z==0) ? WTq : (z==1) ? WTk : WTv;
        int c0 = (bb & 31) * 64;
        #pragma unroll 4
        for (int i = 0; i < 32; ++i) {
            int idx = i*256 + tid;
            int k = idx >> 6, c = idx & 63;
            t[c][k] = W[(size_t)k * HD + c0 + c];
        }
        __syncthreads();
        #pragma unroll 4
        for (int i = 0; i < 32; ++i) {
            int idx = i*256 + tid;
            int c = idx >> 7, k = idx & 127;
            WT[(size_t)(c0 + c) * DD + k] = f2bf(t[c][k]);
        }
    } else {
        int b2 = bb - 96;
        int k0 = (b2 & 15) * 128;
        int j0 = (b2 >> 4) * 64;
        #pragma unroll 4
        for (int i = 0; i < 32; ++i) {
            int idx = i*256 + tid;
            int kk = idx >> 6, jj = idx & 63;
            t[jj][kk] = Wf[(size_t)(k0 + kk) * DD + j0 + jj];
        }
        __syncthreads();
        #pragma unroll 4
        for (int i = 0; i < 32; ++i) {
            int idx = i*256 + tid;
            int jj = idx >> 7, kk = idx & 127;
            float v = t[jj][kk];
            short hb = f2bf(v);
            Whi[(size_t)(j0 + jj) * HD + k0 + kk] = hb;
            Wlo[(size_t)(j0 + jj) * HD + k0 + kk] = f2bf(v - bf2f(hb));
        }
    }
}

// ---- projmask: proj units [0,1536) + mask_perm units [1536,5632) in one grid.
__global__ __launch_bounds__(256, 2) void projmask_kernel(
    const float* __restrict__ Xq, const float* __restrict__ Xk, const float* __restrict__ Xv,
    const float* __restrict__ m,
    const short* __restrict__ WTq, const short* __restrict__ WTk, const short* __restrict__ WTv,
    const float* __restrict__ bq, const float* __restrict__ bk, const float* __restrict__ bv,
    short* __restrict__ Yq, short* __restrict__ Yk, short* __restrict__ Yv,
    unsigned short* __restrict__ mp)
{
    __shared__ alignas(16) char Wl[128 * 256];   // 32 KB
    const int u = blockIdx.x;
    const int tid = threadIdx.x;

    if (u >= 1536) {
        // ---- mask_perm (verified r8 layout), value scaled by log2e ----
        const float LOG2E = 1.44269504088896340736f;
        int o8 = (u - 1536) * 256 + tid;
        int g    = o8 & 3;
        int lane = (o8 >> 2) & 63;
        int kt   = (o8 >> 8) & 31;
        int band = (o8 >> 13) & 63;
        int b    = o8 >> 19;
        int lr = lane & 15, lg = lane >> 4;
        int rt = g >> 1;
        int row  = band*32 + rt*16 + lr;
        int colb = kt*64 + (g & 1)*32 + lg*4;
        const float* src = m + (size_t)b * SS * SS + (size_t)row * SS;
        f32x4 v0 = *reinterpret_cast<const f32x4*>(src + colb);
        f32x4 v1 = *reinterpret_cast<const f32x4*>(src + colb + 16);
        s16x8 o;
        #pragma unroll
        for (int j = 0; j < 4; ++j) { o[j] = f2bf(v0[j]*LOG2E); o[4+j] = f2bf(v1[j]*LOG2E); }
        *reinterpret_cast<s16x8*>(mp + (size_t)o8 * 8) = o;
        return;
    }

    // ---- proj unit ----
    int z = u >> 9;
    int bx = u & 511;
    const float* X  = (z==0) ? Xq  : (z==1) ? Xk  : Xv;
    const short* WT = (z==0) ? WTq : (z==1) ? WTk : WTv;
    const float* bias = (z==0) ? bq : (z==1) ? bk : bv;
    short* Y = (z==0) ? Yq : (z==1) ? Yk : Yv;
    const float oscale = (z==0) ? 0.022097086912079608f : 1.0f;  // 1/sqrt(2048)

    int wave = tid >> 6, lane = tid & 63;
    int lr = lane & 15, lg = lane >> 4;
    int rb = bx >> 4, cb = bx & 15;
    int row0 = rb * 128 + wave * 32;
    int col0 = cb * 128;

    #pragma unroll
    for (int p = 0; p < 8; ++p) {
        int crow = p*16 + (tid >> 4), cc = tid & 15;
        *reinterpret_cast<int4*>(Wl + crow*256 + ((cc ^ (crow & 15)) << 4)) =
            *reinterpret_cast<const int4*>(WT + (size_t)(col0 + crow) * DD + cc*8);
    }
    __syncthreads();

    s16x8 afr[2][4];
    #pragma unroll
    for (int rt = 0; rt < 2; ++rt) {
        const float* xrow = X + (size_t)(row0 + rt*16 + lr) * DD + lg * 8;
        #pragma unroll
        for (int c = 0; c < 4; ++c) {
            f32x4 a0 = *reinterpret_cast<const f32x4*>(xrow + c*32);
            f32x4 a1 = *reinterpret_cast<const f32x4*>(xrow + c*32 + 4);
            #pragma unroll
            for (int j = 0; j < 4; ++j) { afr[rt][c][j] = f2bf(a0[j]); afr[rt][c][4+j] = f2bf(a1[j]); }
        }
    }

    f32x4 acc[2][8];
    #pragma unroll
    for (int rt = 0; rt < 2; ++rt)
        #pragma unroll
        for (int tn = 0; tn < 8; ++tn) acc[rt][tn] = (f32x4){0.f, 0.f, 0.f, 0.f};

    #pragma unroll
    for (int tn = 0; tn < 8; ++tn) {
        s16x8 kf[4];
        #pragma unroll
        for (int c = 0; c < 4; ++c)
            kf[c] = *reinterpret_cast<const s16x8*>(
                Wl + (tn*16 + lr)*256 + (((c*4 + lg) ^ lr) << 4));
        #pragma unroll
        for (int rt = 0; rt < 2; ++rt)
            #pragma unroll
            for (int c = 0; c < 4; ++c)
                acc[rt][tn] = __builtin_amdgcn_mfma_f32_16x16x32_bf16(afr[rt][c], kf[c], acc[rt][tn], 0, 0, 0);
    }

    #pragma unroll
    for (int tn = 0; tn < 8; ++tn) {
        float bcol = bias[col0 + tn*16 + lr];
        #pragma unroll
        for (int rt = 0; rt < 2; ++rt) {
            #pragma unroll
            for (int r = 0; r < 4; ++r) {
                int row = row0 + rt*16 + lg*4 + r;
                Y[(size_t)row * HD + col0 + tn*16 + lr] = f2bf((acc[rt][tn][r] + bcol) * oscale);
            }
        }
    }
}

// ---- transpose Yv -> Vt with sigma (verified r8 math; 8-row/512-block tiling
//      verified inside the round-14 mega-kernel P2).
__global__ __launch_bounds__(256) void vtrans(
    const short* __restrict__ Yv, short* __restrict__ Vt) {
    __shared__ short t16[8 * 2048];    // 32 KB
    int row0 = blockIdx.x * 8;
    int tid = threadIdx.x;
    #pragma unroll
    for (int i = 0; i < 8; ++i) {
        int chunk = i*256 + tid;         // 0..2047
        int rr = chunk >> 8, c8 = chunk & 255;
        *reinterpret_cast<s16x8*>(&t16[rr*2048 + c8*8]) =
            *reinterpret_cast<const s16x8*>(Yv + (size_t)(row0 + rr) * HD + c8*8);
    }
    __syncthreads();
    int bb = row0 >> 11, row2 = row0 & 2047, hh = row2 >> 7, r0 = row2 & 127;
    int s0 = r0 * 16;
    int d = tid & 127, si = tid >> 7;    // si 0..1
    short* outbase = Vt + ((size_t)((bb*HH + hh)*DD + d)) * SS;
    #pragma unroll
    for (int i = 0; i < 4; ++i) {
        int run = s0 + si*64 + i*16;
        int r16 = (run - s0) >> 4;
        short v[16];
        #pragma unroll
        for (int j = 0; j < 16; ++j) v[j] = t16[r16*2048 + j*128 + d];
        int blk = run & ~63;
        int t = (run >> 4) & 3;
        short* dstb = outbase + blk + (t >> 1)*32;
        if ((t & 1) == 0) {
            #pragma unroll
            for (int g = 0; g < 4; ++g) {
                uint2 w;
                w.x = (unsigned)(unsigned short)v[g*4]   | ((unsigned)(unsigned short)v[g*4+1] << 16);
                w.y = (unsigned)(unsigned short)v[g*4+2] | ((unsigned)(unsigned short)v[g*4+3] << 16);
                *reinterpret_cast<uint2*>(dstb + g*8) = w;
            }
        } else {
            #pragma unroll
            for (int g = 0; g < 4; ++g) {
                unsigned p0 = (unsigned)(unsigned short)v[g*4]   | ((unsigned)(unsigned short)v[g*4+1] << 16);
                unsigned p1 = (unsigned)(unsigned short)v[g*4+2] | ((unsigned)(unsigned short)v[g*4+3] << 16);
                int off0 = (g < 2) ? g*8 + 6  : g*8 - 12;
                int off1 = (g < 2) ? g*8 + 22 : g*8 + 4;
                *reinterpret_cast<unsigned*>(dstb + off0) = p0;
                *reinterpret_cast<unsigned*>(dstb + off1) = p1;
            }
        }
    }
}

// ---- fused attention (round-16 verified-best, verbatim): fp32 coalesced Aout.
//      256-thread block = 4 waves, one head x 128 q-rows, 2 blocks/CU.
//      Double-buffered K/V LDS, ONE barrier/iter. Reg-staged prefetch.
//      Swapped QK^T -> in-register P. Permuted bf16 mask (x log2e), raw v_exp_f32.
__global__ __launch_bounds__(256, 2) void attn_kernel(
    const short* __restrict__ Yq, const short* __restrict__ Yk, const short* __restrict__ Vt,
    const unsigned short* __restrict__ Mp, float* __restrict__ Aout)
{
    __shared__ alignas(16) char Kl[2][64 * 256];   // 32 KB
    __shared__ alignas(16) char Vl[2][128 * 128];  // 32 KB

    const int tid = threadIdx.x;
    const int wave = tid >> 6, lane = tid & 63;
    const int lr = lane & 15, lg = lane >> 4;
    const int h = blockIdx.x, qb = blockIdx.y, b = blockIdx.z;
    const int q0w = qb * 128 + wave * 32;
    const int band = qb * 4 + wave;

    const short* Qb = Yq + (size_t)(b*HH + h) * (SS*DD);
    const short* Kb = Yk + (size_t)(b*HH + h) * (SS*DD);
    const short* Vb = Vt + (size_t)(b*HH + h) * (SS*DD);
    const unsigned short* mrow = Mp + ((size_t)(b*64 + band) * 2048 + lane) * 32;

    // --- staging geometry: per thread 4 K chunks + 4 V chunks of 16B ---
    int kdst[4], vdst[4];
    const short* ksrc[4];
    const short* vsrc[4];
    #pragma unroll
    for (int p = 0; p < 4; ++p) {
        int krow = p*16 + (tid >> 4), kc16 = tid & 15;
        kdst[p] = krow*256 + ((kc16 ^ (krow & 15)) << 4);
        ksrc[p] = Kb + (size_t)krow * DD + kc16*8;
        int vd = p*32 + (tid >> 3), vc8 = tid & 7;
        vdst[p] = vd*128 + ((vc8 ^ (vd & 7)) << 4);
        vsrc[p] = Vb + (size_t)vd * SS + vc8*8;
    }

    // --- Q fragments (B-operand; pre-scaled by 1/sqrt(S)) ---
    s16x8 qf[2][4];
    #pragma unroll
    for (int rt = 0; rt < 2; ++rt) {
        const short* qrow = Qb + (size_t)(q0w + rt*16 + lr) * DD + lg * 8;
        #pragma unroll
        for (int c = 0; c < 4; ++c) qf[rt][c] = *reinterpret_cast<const s16x8*>(qrow + c*32);
    }

    f32x4 o[2][8];
    #pragma unroll
    for (int rt = 0; rt < 2; ++rt)
        #pragma unroll
        for (int dt = 0; dt < 8; ++dt) o[rt][dt] = (f32x4){0.f, 0.f, 0.f, 0.f};
    float ls[2] = {0.f, 0.f};

    // --- prologue: stage tile 0 into buffer 0 ---
    #pragma unroll
    for (int p = 0; p < 4; ++p) {
        *reinterpret_cast<int4*>(Kl[0] + kdst[p]) = *reinterpret_cast<const int4*>(ksrc[p]);
        *reinterpret_cast<int4*>(Vl[0] + vdst[p]) = *reinterpret_cast<const int4*>(vsrc[p]);
    }
    __syncthreads();

    for (int kt = 0; kt < 32; ++kt) {
        const int cur = kt & 1;
        char* Klc = Kl[cur];     char* Vlc = Vl[cur];
        char* Kln = Kl[cur ^ 1]; char* Vln = Vl[cur ^ 1];
        const int kp0 = kt * 64;
        const int kpn = (kt < 31) ? kp0 + 64 : kp0;

        // prefetch next tile into regs
        int4 kreg[4], vreg[4];
        #pragma unroll
        for (int p = 0; p < 4; ++p) {
            kreg[p] = *reinterpret_cast<const int4*>(ksrc[p] + (size_t)kpn * DD);
            vreg[p] = *reinterpret_cast<const int4*>(vsrc[p] + kpn);
        }

        // permuted mask: 4 contiguous b128 loads
        const unsigned short* mptr = mrow + (size_t)kt * 2048;
        s16x8 mk[4];
        mk[0] = *reinterpret_cast<const s16x8*>(mptr);
        mk[1] = *reinterpret_cast<const s16x8*>(mptr + 8);
        mk[2] = *reinterpret_cast<const s16x8*>(mptr + 16);
        mk[3] = *reinterpret_cast<const s16x8*>(mptr + 24);

        // SWAPPED QK^T: lane (lr,lg) reg r = score[q=rt*16+lr][k=t*16+lg*4+r]
        f32x4 st[2][4];
        #pragma unroll
        for (int rt = 0; rt < 2; ++rt)
            #pragma unroll
            for (int t = 0; t < 4; ++t) st[rt][t] = (f32x4){0.f, 0.f, 0.f, 0.f};
        __builtin_amdgcn_s_setprio(1);
        #pragma unroll
        for (int t = 0; t < 4; ++t) {
            s16x8 kf[4];
            #pragma unroll
            for (int c = 0; c < 4; ++c)
                kf[c] = *reinterpret_cast<const s16x8*>(
                    Klc + (t*16 + lr)*256 + (((c*4 + lg) ^ lr) << 4));
            #pragma unroll
            for (int rt = 0; rt < 2; ++rt)
                #pragma unroll
                for (int c = 0; c < 4; ++c)
                    st[rt][t] = __builtin_amdgcn_mfma_f32_16x16x32_bf16(kf[c], qf[rt][c], st[rt][t], 0, 0, 0);
        }
        __builtin_amdgcn_s_setprio(0);

        // mask-mul + raw v_exp_f32 (mask pre-scaled by log2e; |arg| <= ~2.2)
        #pragma unroll
        for (int rt = 0; rt < 2; ++rt) {
            float ps = 0.f;
            #pragma unroll
            for (int t = 0; t < 4; ++t) {
                #pragma unroll
                for (int r = 0; r < 4; ++r) {
                    float mvv = us2f((unsigned short)mk[rt*2 + (t>>1)][(t&1)*4 + r]);
                    st[rt][t][r] = __builtin_amdgcn_exp2f(st[rt][t][r] * mvv);
                    ps += st[rt][t][r];
                }
            }
            ls[rt] += ps;
        }

        // in-register P -> A-frags (verified construction)
        s16x8 pfr[2][2];
        #pragma unroll
        for (int rt = 0; rt < 2; ++rt) {
            #pragma unroll
            for (int c2 = 0; c2 < 2; ++c2) {
                union { unsigned u[4]; s16x8 s; } pk;
                pk.u[0] = cvtpk(st[rt][c2*2][0],   st[rt][c2*2][1]);
                pk.u[1] = cvtpk(st[rt][c2*2][2],   st[rt][c2*2][3]);
                unsigned X = cvtpk(st[rt][c2*2+1][0], st[rt][c2*2+1][1]);
                unsigned Y = cvtpk(st[rt][c2*2+1][2], st[rt][c2*2+1][3]);
                asm("v_permlane32_swap_b32 %0, %1" : "+v"(X), "+v"(Y));
                pk.u[2] = Y;
                pk.u[3] = X;
                pfr[rt][c2] = pk.s;
            }
        }

        // PV: V frags (sigma-permuted) read once, shared across row-tiles
        __builtin_amdgcn_s_setprio(1);
        #pragma unroll
        for (int dt = 0; dt < 8; ++dt) {
            const char* vbase = Vlc + (dt*16 + lr)*128;
            s16x8 vf0 = *reinterpret_cast<const s16x8*>(vbase + (((0*4 + lg) ^ (lr & 7)) << 4));
            s16x8 vf1 = *reinterpret_cast<const s16x8*>(vbase + (((1*4 + lg) ^ (lr & 7)) << 4));
            #pragma unroll
            for (int rt = 0; rt < 2; ++rt) {
                o[rt][dt] = __builtin_amdgcn_mfma_f32_16x16x32_bf16(pfr[rt][0], vf0, o[rt][dt], 0, 0, 0);
                o[rt][dt] = __builtin_amdgcn_mfma_f32_16x16x32_bf16(pfr[rt][1], vf1, o[rt][dt], 0, 0, 0);
            }
        }
        __builtin_amdgcn_s_setprio(0);

        // write next tile; ONE barrier per iteration
        #pragma unroll
        for (int p = 0; p < 4; ++p) {
            *reinterpret_cast<int4*>(Kln + kdst[p]) = kreg[p];
            *reinterpret_cast<int4*>(Vln + vdst[p]) = vreg[p];
        }
        __syncthreads();
    }

    // epilogue: reduce row-sums, normalize, coalesced fp32 stores
    #pragma unroll
    for (int rt = 0; rt < 2; ++rt) {
        float s = ls[rt];
        s += __shfl_xor(s, 16, 64);
        s += __shfl_xor(s, 32, 64);
        float* orow = Aout + ((size_t)(b*HH + h) * SS + q0w + rt*16) * DD;
        #pragma unroll
        for (int r = 0; r < 4; ++r) {
            float inv = 1.0f / __shfl(s, lg*4 + r, 16);
            #pragma unroll
            for (int dt = 0; dt < 8; ++dt)
                orow[(size_t)(lg*4 + r) * DD + dt*16 + lr] = o[rt][dt][r] * inv;
        }
    }
}

// ---- final GEMM (round-16 verbatim): out = A(fp32)[4096][2048] @ Wf + bf.
//      A converted to bf16 in-kernel (lo dropped, verified r13), W hi/lo.
//      4 waves split K (512 each); parallel LDS reduce + store (2 tn per wave).
__global__ __launch_bounds__(256) void final_gemm(
    const float* __restrict__ A, const short* __restrict__ Whi, const short* __restrict__ Wlo,
    const float* __restrict__ bfv, float* __restrict__ out)
{
    __shared__ float red[4][2048];   // 32 KB
    int wave = threadIdx.x >> 6, lane = threadIdx.x & 63;
    int lr = lane & 15, lg = lane >> 4;
    int row0 = blockIdx.x * 16;
    int k0 = wave * 512;

    f32x4 acc[8];
    #pragma unroll
    for (int tn = 0; tn < 8; ++tn) acc[tn] = (f32x4){0.f, 0.f, 0.f, 0.f};

    const float* arow = A + (size_t)(row0 + lr) * HD + k0 + lg * 8;
    for (int kc = 0; kc < 16; ++kc) {
        s16x8 ah;
        f32x4 av0 = *reinterpret_cast<const f32x4*>(arow + kc*32);
        f32x4 av1 = *reinterpret_cast<const f32x4*>(arow + kc*32 + 4);
        #pragma unroll
        for (int j = 0; j < 4; ++j) {
            ah[j]   = f2bf(av0[j]);
            ah[4+j] = f2bf(av1[j]);
        }
        #pragma unroll
        for (int tn = 0; tn < 8; ++tn) {
            const short* whrow = Whi + (size_t)(tn*16 + lr) * HD + k0 + kc*32 + lg*8;
            const short* wlrow = Wlo + (size_t)(tn*16 + lr) * HD + k0 + kc*32 + lg*8;
            s16x8 bh = *reinterpret_cast<const s16x8*>(whrow);
            s16x8 bl = *reinterpret_cast<const s16x8*>(wlrow);
            acc[tn] = __builtin_amdgcn_mfma_f32_16x16x32_bf16(ah, bh, acc[tn], 0, 0, 0);
            acc[tn] = __builtin_amdgcn_mfma_f32_16x16x32_bf16(ah, bl, acc[tn], 0, 0, 0);
        }
    }

    float* rp = red[wave];
    #pragma unroll
    for (int tn = 0; tn < 8; ++tn)
        *reinterpret_cast<f32x4*>(&rp[(tn*64 + lane)*4]) = acc[tn];
    __syncthreads();

    #pragma unroll
    for (int t2 = 0; t2 < 2; ++t2) {
        int tn = wave*2 + t2;
        f32x4 s = *reinterpret_cast<const f32x4*>(&red[0][(tn*64 + lane)*4]);
        #pragma unroll
        for (int w2 = 1; w2 < 4; ++w2)
            s += *reinterpret_cast<const f32x4*>(&red[w2][(tn*64 + lane)*4]);
        float bc = bfv[tn*16 + lr];
        #pragma unroll
        for (int r = 0; r < 4; ++r)
            out[(size_t)(row0 + lg*4 + r) * DD + tn*16 + lr] = s[r] + bc;
    }
}

extern "C" void kernel_launch(void* const* d_in, const int* in_sizes, int n_in,
                              void* d_out, int out_size, void* d_ws, size_t ws_size,
                              hipStream_t stream) {
    const float* v    = (const float*)d_in[0];
    const float* k    = (const float*)d_in[1];
    const float* q    = (const float*)d_in[2];
    const float* mask = (const float*)d_in[3];
    const float* Wq   = (const float*)d_in[4];
    const float* bq   = (const float*)d_in[5];
    const float* Wk   = (const float*)d_in[6];
    const float* bk   = (const float*)d_in[7];
    const float* Wv   = (const float*)d_in[8];
    const float* bv   = (const float*)d_in[9];
    const float* Wf   = (const float*)d_in[10];
    const float* bf   = (const float*)d_in[11];
    float* out = (float*)d_out;

    char* ws = (char*)d_ws;
    size_t off = 0;
    short* Yq   = (short*)(ws + off); off += (size_t)BS * HD * 2;   // 16 MB
    short* Yk   = (short*)(ws + off); off += (size_t)BS * HD * 2;   // 16 MB
    short* Vt   = (short*)(ws + off); off += (size_t)BS * HD * 2;   // 16 MB
    float* Aout = (float*)(ws + off); off += (size_t)BS * HD * 4;   // 33.5 MB
    short* Yv   = (short*)Aout;                                     // aliases Aout (sequential use)
    unsigned short* Mp = (unsigned short*)(ws + off); off += (size_t)BB * SS * SS * 2; // 16.8 MB
    short* WTq  = (short*)(ws + off); off += (size_t)HD * DD * 2;
    short* WTk  = (short*)(ws + off); off += (size_t)HD * DD * 2;
    short* WTv  = (short*)(ws + off); off += (size_t)HD * DD * 2;
    short* Wfhi = (short*)(ws + off); off += (size_t)DD * HD * 2;
    short* Wflo = (short*)(ws + off); off += (size_t)DD * HD * 2;

    prep_w<<<dim3(128), 256, 0, stream>>>(Wq, Wk, Wv, Wf, WTq, WTk, WTv, Wfhi, Wflo);
    projmask_kernel<<<dim3(5632), 256, 0, stream>>>(q, k, v, mask, WTq, WTk, WTv,
                                                    bq, bk, bv, Yq, Yk, Yv, Mp);
    vtrans<<<dim3(512), 256, 0, stream>>>(Yv, Vt);
    attn_kernel<<<dim3(16, 16, 2), 256, 0, stream>>>(Yq, Yk, Vt, Mp, Aout);
    final_gemm<<<dim3(256), 256, 0, stream>>>(Aout, Wfhi, Wflo, bf, out);
}